// Round 1
// baseline (2876.919 us; speedup 1.0000x reference)
//
#include <hip/hip_runtime.h>
#include <hip/hip_fp16.h>

#define B_ 64
#define M_ 512
#define N_ 512
#define D_ 128
constexpr float EPS_ = 0.05f;
constexpr float SHIFT_ = 1.0f;   // K' = exp((SHIFT - D)/EPS): keeps fp16 range happy
constexpr int NIT_ = 200;

// ---------------------------------------------------------------------------
// Row norms: xn[b,i] = sum_d x^2, yn[b,j] = sum_d y^2. One wave per row.
__global__ __launch_bounds__(256) void wmd_norms(const float* __restrict__ x,
                                                 const float* __restrict__ y,
                                                 float* __restrict__ xn,
                                                 float* __restrict__ yn) {
    int gw = (int)((blockIdx.x * blockDim.x + threadIdx.x) >> 6);
    int l = threadIdx.x & 63;
    const float* src; float* dst; int row;
    if (gw < B_ * M_) { src = x; dst = xn; row = gw; }
    else              { src = y; dst = yn; row = gw - B_ * M_; }
    float2 a = ((const float2*)(src + (size_t)row * D_))[l];
    float s = a.x * a.x + a.y * a.y;
#pragma unroll
    for (int off = 32; off; off >>= 1) s += __shfl_xor(s, off);
    if (l == 0) dst[row] = s;
}

// ---------------------------------------------------------------------------
// Build K'[b,i,j] = clamp(exp((SHIFT - D_ij)/EPS)) in fp16.
// D_ij = sqrt(max((xn_i + yn_j - 2 x.y)/D_, 1e-12)) — same formula as reference.
__global__ __launch_bounds__(256) void wmd_build_k(const float* __restrict__ x,
                                                   const float* __restrict__ y,
                                                   const float* __restrict__ xn,
                                                   const float* __restrict__ yn,
                                                   __half* __restrict__ Kp) {
    int b = blockIdx.z, it = blockIdx.y, jt = blockIdx.x;
    __shared__ float xs[32][129];
    __shared__ float ys[32][129];
    const float4* xb = (const float4*)(x + ((size_t)b * M_ + it * 32) * D_);
    const float4* yb = (const float4*)(y + ((size_t)b * N_ + jt * 32) * D_);
    int t = threadIdx.x;
#pragma unroll
    for (int k = 0; k < 4; ++k) {
        int idx = t + k * 256;            // float4 index into 32x128 tile
        int r = idx >> 5, c = (idx & 31) * 4;
        float4 vx = xb[idx];
        float4 vy = yb[idx];
        xs[r][c] = vx.x; xs[r][c + 1] = vx.y; xs[r][c + 2] = vx.z; xs[r][c + 3] = vx.w;
        ys[r][c] = vy.x; ys[r][c + 1] = vy.y; ys[r][c + 2] = vy.z; ys[r][c + 3] = vy.w;
    }
    __syncthreads();
    int ti = t >> 5, tj = t & 31;
    float a0 = 0.f, a1 = 0.f, a2 = 0.f, a3 = 0.f;
    for (int d = 0; d < D_; ++d) {
        float yv = ys[tj][d];
        a0 += xs[ti][d] * yv;
        a1 += xs[ti + 8][d] * yv;
        a2 += xs[ti + 16][d] * yv;
        a3 += xs[ti + 24][d] * yv;
    }
    float ynj = yn[(size_t)b * N_ + jt * 32 + tj];
    float accs[4] = {a0, a1, a2, a3};
#pragma unroll
    for (int k = 0; k < 4; ++k) {
        int gi = it * 32 + ti + 8 * k;
        float sq = (xn[(size_t)b * M_ + gi] + ynj - 2.0f * accs[k]) * (1.0f / D_);
        float Dv = sqrtf(fmaxf(sq, 1e-12f));
        float kv = expf((SHIFT_ - Dv) * (1.0f / EPS_));
        kv = fmaxf(kv, 1e-7f);            // avoid fp16 underflow to 0 (0*inf in final pass)
        Kp[((size_t)b * M_ + gi) * N_ + jt * 32 + tj] = __float2half(kv);
    }
}

// ---------------------------------------------------------------------------
// Persistent Sinkhorn: 1 workgroup (16 waves) per batch.
// Per iteration: wave w owns rows {w, w+16, ...}: dot(K'_i, v) -> u_i, and
// accumulates colacc_j += K'_ij * u_i in registers (lane owns cols 8l..8l+7).
// One LDS merge of 16 partials -> v. K' read exactly once per iteration.
__global__ __launch_bounds__(1024, 1) void wmd_sinkhorn(const __half* __restrict__ K,
                                                        float* __restrict__ wmd) {
    int b = blockIdx.x;
    const __half* Kb = K + (size_t)b * M_ * N_;
    __shared__ float v_s[N_];
    __shared__ float u_s[M_];
    __shared__ float mrg[16][N_];
    __shared__ float wsum[16];
    int t = threadIdx.x, w = t >> 6, l = t & 63;
    for (int j = t; j < N_; j += 1024) v_s[j] = 1.0f;   // v0 = exp(g0/eps) = 1
    __syncthreads();
    const float pmarg = 1.0f / M_, qmarg = 1.0f / N_;
#pragma unroll 1
    for (int it = 0; it < NIT_; ++it) {
        float ca0 = 0.f, ca1 = 0.f, ca2 = 0.f, ca3 = 0.f;
        float ca4 = 0.f, ca5 = 0.f, ca6 = 0.f, ca7 = 0.f;
        for (int i = w; i < M_; i += 16) {
            const __half* rp = Kb + (size_t)i * N_ + l * 8;
            uint4 kq = *(const uint4*)rp;
            const __half2* h2 = (const __half2*)&kq;
            float2 f0 = __half22float2(h2[0]);
            float2 f1 = __half22float2(h2[1]);
            float2 f2 = __half22float2(h2[2]);
            float2 f3 = __half22float2(h2[3]);
            float4 va = *(const float4*)&v_s[l * 8];
            float4 vb = *(const float4*)&v_s[l * 8 + 4];
            float dot = f0.x * va.x + f0.y * va.y + f1.x * va.z + f1.y * va.w
                      + f2.x * vb.x + f2.y * vb.y + f3.x * vb.z + f3.y * vb.w;
#pragma unroll
            for (int off = 32; off; off >>= 1) dot += __shfl_xor(dot, off);
            float u = pmarg * __builtin_amdgcn_rcpf(dot);
            if (l == 0) u_s[i] = u;
            ca0 += f0.x * u; ca1 += f0.y * u; ca2 += f1.x * u; ca3 += f1.y * u;
            ca4 += f2.x * u; ca5 += f2.y * u; ca6 += f3.x * u; ca7 += f3.y * u;
        }
        *(float4*)&mrg[w][l * 8]     = make_float4(ca0, ca1, ca2, ca3);
        *(float4*)&mrg[w][l * 8 + 4] = make_float4(ca4, ca5, ca6, ca7);
        __syncthreads();
        if (t < N_) {
            float s = 0.f;
#pragma unroll
            for (int ww = 0; ww < 16; ++ww) s += mrg[ww][t];
            v_s[t] = qmarg * __builtin_amdgcn_rcpf(s);
        }
        __syncthreads();
    }
    // Final: wmd_b = sum_ij u_i K'_ij v_j * D_ij,  D_ij = SHIFT - EPS*ln(K'_ij)
    float acc = 0.0f;
    for (int i = w; i < M_; i += 16) {
        const __half* rp = Kb + (size_t)i * N_ + l * 8;
        uint4 kq = *(const uint4*)rp;
        const __half2* h2 = (const __half2*)&kq;
        float2 f0 = __half22float2(h2[0]);
        float2 f1 = __half22float2(h2[1]);
        float2 f2 = __half22float2(h2[2]);
        float2 f3 = __half22float2(h2[3]);
        float kf[8] = {f0.x, f0.y, f1.x, f1.y, f2.x, f2.y, f3.x, f3.y};
        float4 va = *(const float4*)&v_s[l * 8];
        float4 vb = *(const float4*)&v_s[l * 8 + 4];
        float vv[8] = {va.x, va.y, va.z, va.w, vb.x, vb.y, vb.z, vb.w};
        float u = u_s[i];
#pragma unroll
        for (int e = 0; e < 8; ++e) {
            float Dv = SHIFT_ - EPS_ * __logf(kf[e]);
            acc += (u * kf[e] * vv[e]) * Dv;
        }
    }
#pragma unroll
    for (int off = 32; off; off >>= 1) acc += __shfl_xor(acc, off);
    if (l == 0) wsum[w] = acc;
    __syncthreads();
    if (t == 0) {
        float s = 0.f;
#pragma unroll
        for (int ww = 0; ww < 16; ++ww) s += wsum[ww];
        wmd[b] = s;
    }
}

// ---------------------------------------------------------------------------
__global__ void wmd_mse(const float* __restrict__ wmd, const float* __restrict__ labels,
                        float* __restrict__ out) {
    int l = threadIdx.x;
    float d = wmd[l] - labels[l];
    d = d * d;
#pragma unroll
    for (int off = 32; off; off >>= 1) d += __shfl_xor(d, off);
    if (l == 0) out[0] = d * (1.0f / B_);
}

// ---------------------------------------------------------------------------
extern "C" void kernel_launch(void* const* d_in, const int* in_sizes, int n_in,
                              void* d_out, int out_size, void* d_ws, size_t ws_size,
                              hipStream_t stream) {
    const float* x = (const float*)d_in[0];
    const float* y = (const float*)d_in[1];
    const float* labels = (const float*)d_in[2];
    float* out = (float*)d_out;

    char* ws = (char*)d_ws;
    __half* K = (__half*)ws;                                  // 32 MiB
    float* xn = (float*)(ws + (size_t)B_ * M_ * N_ * sizeof(__half));
    float* yn = xn + (size_t)B_ * M_;
    float* wmd = yn + (size_t)B_ * N_;

    wmd_norms<<<(B_ * (M_ + N_)) / 4, 256, 0, stream>>>(x, y, xn, yn);
    wmd_build_k<<<dim3(N_ / 32, M_ / 32, B_), 256, 0, stream>>>(x, y, xn, yn, K);
    wmd_sinkhorn<<<B_, 1024, 0, stream>>>(K, wmd);
    wmd_mse<<<1, 64, 0, stream>>>(wmd, labels, out);
}